// Round 9
// baseline (412.419 us; speedup 1.0000x reference)
//
#include <hip/hip_runtime.h>
#include <hip/hip_bf16.h>
#include <math.h>

#define N_NODES 50000
#define N_EDGES 800000
#define IN_F 256
#define OUT_F 64
#define ALPHA 0.2f

#define NPB 128                 // nodes per bucket
#define NBKT 391                // ceil(50000/128)
#define CAP 2560                // bucket capacity (mean 2048 + ~11 sigma)
#define BIN_EPB 4096
#define BIN_NB 196              // ceil(800000/4096)
#define GEMM_NB 391             // ceil(50000/128)

typedef __attribute__((ext_vector_type(8))) short short8;
typedef __attribute__((ext_vector_type(4))) float f32x4;

__device__ __forceinline__ unsigned short f2b(float f) {
    unsigned u = __float_as_uint(f);
    unsigned r = (u + 0x7fffu + ((u >> 16) & 1u)) >> 16;  // RNE
    return (unsigned short)r;
}
__device__ __forceinline__ float b2f(unsigned short b) {
    return __uint_as_float(((unsigned)b) << 16);
}
__device__ __forceinline__ unsigned cvt2(float a, float b) {
    __hip_bfloat162 h2 = __float22bfloat162_rn(make_float2(a, b));
    return *reinterpret_cast<unsigned*>(&h2);
}

union abits {
    short8 s8;
    unsigned u[4];
};

// prep: W -> bf16 MFMA B-fragments; also inits gcursor (NBKT entries).
__global__ __launch_bounds__(256) void k_wprep(const float* __restrict__ W,
                                               short* __restrict__ Wfrag,
                                               int* __restrict__ gcursor) {
    int idx = blockIdx.x * 256 + threadIdx.x;  // 64 blocks -> 16384
    if (idx < NBKT) gcursor[idx] = idx * CAP;
    if (idx >= 8 * 4 * 64 * 8) return;
    int j = idx & 7;
    int l = (idx >> 3) & 63;
    int t = (idx >> 9) & 3;
    int s = idx >> 11;
    int k = s * 32 + (l >> 4) * 8 + j;
    int n = t * 16 + (l & 15);
    Wfrag[idx] = (short)f2b(W[k * OUT_F + n]);
}

// Fused: blocks [0,BIN_NB) bin edges into bucket regions (src>>7);
//        blocks [BIN_NB, BIN_NB+GEMM_NB) do the MFMA GEMM.
__global__ __launch_bounds__(256, 2) void k_bc(
    const float* __restrict__ h, const short* __restrict__ Wfrag,
    const float* __restrict__ a, unsigned short* __restrict__ Whb,
    float* __restrict__ ew, const int* __restrict__ ei,
    int* __restrict__ gcursor, int* __restrict__ binned) {
    __shared__ int bc[NBKT];

    if (blockIdx.x < BIN_NB) {
        // ---- binning branch ----
        const int t = threadIdx.x;
        for (int i = t; i < NBKT; i += 256) bc[i] = 0;
        __syncthreads();

        int s[16], d[16];
        const int e0 = blockIdx.x * BIN_EPB;
#pragma unroll
        for (int i = 0; i < 16; ++i) {
            int e = e0 + i * 256 + t;
            if (e < N_EDGES) {
                s[i] = ei[e];
                d[i] = ei[N_EDGES + e];
                atomicAdd(&bc[s[i] >> 7], 1);
            } else {
                s[i] = -1;
            }
        }
        __syncthreads();
        for (int i = t; i < NBKT; i += 256) {
            int cnt = bc[i];
            bc[i] = cnt ? atomicAdd(&gcursor[i], cnt) : 0;
        }
        __syncthreads();
#pragma unroll
        for (int i = 0; i < 16; ++i) {
            if (s[i] >= 0) {
                int bkt = s[i] >> 7;
                int idx = atomicAdd(&bc[bkt], 1);
                if (idx < (bkt + 1) * CAP)
                    binned[idx] = ((s[i] & 127) << 16) | d[i];
            }
        }
        return;
    }

    // ---- GEMM branch: Wh(bf16) = leaky_relu(h@W); ew = exp(Wh@a2) ----
    const int bid = blockIdx.x - BIN_NB;
    const int tid = threadIdx.x;
    const int wid = tid >> 6;
    const int l = tid & 63;
    const int lo = l & 15;
    const int g = l >> 4;
    const int m0 = (bid * 4 + wid) * 32;

    short8 b[8][4];
#pragma unroll
    for (int s = 0; s < 8; ++s)
#pragma unroll
        for (int t = 0; t < 4; ++t)
            b[s][t] = *(const short8*)&Wfrag[(((s * 4 + t) * 64) + l) * 8];

    const int r0 = m0 + lo;
    const int r1 = m0 + 16 + lo;
    const int r0c = r0 < N_NODES ? r0 : N_NODES - 1;
    const int r1c = r1 < N_NODES ? r1 : N_NODES - 1;

    f32x4 acc[2][4];
#pragma unroll
    for (int mt = 0; mt < 2; ++mt)
#pragma unroll
        for (int t = 0; t < 4; ++t)
            acc[mt][t] = (f32x4){0.f, 0.f, 0.f, 0.f};

#pragma unroll
    for (int s = 0; s < 8; ++s) {
        const float* p0 = &h[(size_t)r0c * IN_F + s * 32 + g * 8];
        const float* p1 = &h[(size_t)r1c * IN_F + s * 32 + g * 8];
        float4 x0 = *(const float4*)p0;
        float4 y0 = *(const float4*)(p0 + 4);
        float4 x1 = *(const float4*)p1;
        float4 y1 = *(const float4*)(p1 + 4);
        abits A0, A1;
        A0.u[0] = cvt2(x0.x, x0.y);
        A0.u[1] = cvt2(x0.z, x0.w);
        A0.u[2] = cvt2(y0.x, y0.y);
        A0.u[3] = cvt2(y0.z, y0.w);
        A1.u[0] = cvt2(x1.x, x1.y);
        A1.u[1] = cvt2(x1.z, x1.w);
        A1.u[2] = cvt2(y1.x, y1.y);
        A1.u[3] = cvt2(y1.z, y1.w);
#pragma unroll
        for (int t = 0; t < 4; ++t) {
            acc[0][t] = __builtin_amdgcn_mfma_f32_16x16x32_bf16(
                A0.s8, b[s][t], acc[0][t], 0, 0, 0);
            acc[1][t] = __builtin_amdgcn_mfma_f32_16x16x32_bf16(
                A1.s8, b[s][t], acc[1][t], 0, 0, 0);
        }
    }

    float a2v[4];
#pragma unroll
    for (int t = 0; t < 4; ++t) a2v[t] = a[OUT_F + t * 16 + lo];

#pragma unroll
    for (int mt = 0; mt < 2; ++mt) {
        float p[4];
#pragma unroll
        for (int reg = 0; reg < 4; ++reg) {
            float pp = 0.f;
#pragma unroll
            for (int t = 0; t < 4; ++t) {
                float v = acc[mt][t][reg];
                v = v > 0.f ? v : ALPHA * v;
                acc[mt][t][reg] = v;
                pp += v * a2v[t];
            }
            p[reg] = pp;
        }
#pragma unroll
        for (int reg = 0; reg < 4; ++reg) {
#pragma unroll
            for (int mask = 1; mask < 16; mask <<= 1)
                p[reg] += __shfl_xor(p[reg], mask, 64);
        }
        const int rbase = m0 + mt * 16 + g * 4;
        if (lo == 0) {
#pragma unroll
            for (int reg = 0; reg < 4; ++reg)
                if (rbase + reg < N_NODES) ew[rbase + reg] = __expf(p[reg]);
        }
#pragma unroll
        for (int reg = 0; reg < 4; ++reg) {
            int r = rbase + reg;
            if (r < N_NODES) {
#pragma unroll
                for (int t = 0; t < 4; ++t)
                    Whb[(size_t)r * OUT_F + t * 16 + lo] =
                        f2b(acc[mt][t][reg]);
            }
        }
    }
}

// Fused aggregate: one block per 128-node bucket. No sort — direct LDS
// accumulation: acc[128][64] f32 + den[128], ds_add_f32 per edge-feature.
__global__ __launch_bounds__(1024) void k_fuse(
    const int* __restrict__ binned, const int* __restrict__ gcursor,
    const float* __restrict__ ew, const unsigned short* __restrict__ Whb,
    float* __restrict__ out) {
    __shared__ float accL[NPB * OUT_F];   // 32 KB
    __shared__ float denL[NPB];
    const int t = threadIdx.x;
    const int b = blockIdx.x;
    const int wave = t >> 6;
    const int lane = t & 63;

    int mycnt = gcursor[b] - b * CAP;
    mycnt = mycnt < 0 ? 0 : (mycnt > CAP ? CAP : mycnt);
    const int rb = b * CAP;

    for (int i = t; i < NPB * OUT_F; i += 1024) accL[i] = 0.f;
    if (t < NPB) denL[t] = 0.f;
    __syncthreads();

    // each wave takes a contiguous chunk; 64-edge register batches
    const int chunk = (mycnt + 15) >> 4;
    const int begin = wave * chunk;
    const int endw = (begin + chunk < mycnt) ? begin + chunk : mycnt;

    for (int j0 = begin; j0 < endw; j0 += 64) {
        int myj = j0 + lane;
        int pk = (myj < endw) ? binned[rb + myj] : 0;
        float wv = ew[pk & 0xFFFF];           // per-lane gather (batched)
        int n = endw - j0;
        n = n > 64 ? 64 : n;
        for (int u = 0; u < n; ++u) {
            int pku = __shfl(pk, u, 64);
            float wu = __shfl(wv, u, 64);
            int sl = pku >> 16;
            int dd = pku & 0xFFFF;
            float v = b2f(Whb[(size_t)dd * OUT_F + lane]);
            atomicAdd(&accL[sl * OUT_F + lane], wu * v);
            if (lane == 0) atomicAdd(&denL[sl], wu);
        }
    }
    __syncthreads();

    // epilogue: 8 consecutive features per thread, 2x float4 stores
    {
        int i0 = t * 8;                       // < 8192
        int nd = i0 >> 6;
        int f0 = i0 & 63;
        int node = b * NPB + nd;
        if (node < N_NODES) {
            float dn = denL[nd];
            float inv = dn > 0.f ? 1.f / dn : 0.f;
            float4 r0, r1;
            float v;
            v = accL[nd * OUT_F + f0 + 0] * inv; r0.x = v > 0.f ? v : expm1f(v);
            v = accL[nd * OUT_F + f0 + 1] * inv; r0.y = v > 0.f ? v : expm1f(v);
            v = accL[nd * OUT_F + f0 + 2] * inv; r0.z = v > 0.f ? v : expm1f(v);
            v = accL[nd * OUT_F + f0 + 3] * inv; r0.w = v > 0.f ? v : expm1f(v);
            v = accL[nd * OUT_F + f0 + 4] * inv; r1.x = v > 0.f ? v : expm1f(v);
            v = accL[nd * OUT_F + f0 + 5] * inv; r1.y = v > 0.f ? v : expm1f(v);
            v = accL[nd * OUT_F + f0 + 6] * inv; r1.z = v > 0.f ? v : expm1f(v);
            v = accL[nd * OUT_F + f0 + 7] * inv; r1.w = v > 0.f ? v : expm1f(v);
            *(float4*)&out[(size_t)node * OUT_F + f0] = r0;
            *(float4*)&out[(size_t)node * OUT_F + f0 + 4] = r1;
        }
    }
}

extern "C" void kernel_launch(void* const* d_in, const int* in_sizes, int n_in,
                              void* d_out, int out_size, void* d_ws,
                              size_t ws_size, hipStream_t stream) {
    const float* h = (const float*)d_in[0];
    const int* ei = (const int*)d_in[1];
    const float* W = (const float*)d_in[2];
    const float* a = (const float*)d_in[3];
    float* out = (float*)d_out;

    float* ws = (float*)d_ws;
    unsigned short* Whb = (unsigned short*)ws;   // 3.2M bf16 = 1.6M floats
    float* ew = ws + 1600000;                    // 50,000
    short* Wfrag = (short*)(ws + 1650000);       // 16,384 bf16
    int* gcursor = (int*)(ws + 1658192);         // 512 (NBKT=391 used)
    int* binned = (int*)(ws + 1658704);          // NBKT*CAP = 1,000,960 ints

    k_wprep<<<64, 256, 0, stream>>>(W, Wfrag, gcursor);
    k_bc<<<BIN_NB + GEMM_NB, 256, 0, stream>>>(h, Wfrag, a, Whb, ew, ei,
                                               gcursor, binned);
    k_fuse<<<NBKT, 1024, 0, stream>>>(binned, gcursor, ew, Whb, out);
}

// Round 10
// 65.648 us; speedup vs baseline: 6.2823x; 6.2823x over previous
//
#include <hip/hip_runtime.h>
#include <hip/hip_bf16.h>
#include <math.h>

#define N_NODES 50000
#define N_EDGES 800000
#define IN_F 256
#define OUT_F 64
#define ALPHA 0.2f

#define NPB 128                 // nodes per bucket
#define NBKT 391                // ceil(50000/128)
#define CAP 2560                // bucket capacity (mean 2048 + ~11 sigma)
#define BIN_EPB 4096
#define BIN_NB 196              // ceil(800000/4096)
#define GEMM_NB 391             // ceil(50000/128)

typedef __attribute__((ext_vector_type(8))) short short8;
typedef __attribute__((ext_vector_type(8))) unsigned short u16x8;
typedef __attribute__((ext_vector_type(4))) float f32x4;

__device__ __forceinline__ unsigned short f2b(float f) {
    unsigned u = __float_as_uint(f);
    unsigned r = (u + 0x7fffu + ((u >> 16) & 1u)) >> 16;  // RNE
    return (unsigned short)r;
}
__device__ __forceinline__ float b2f(unsigned short b) {
    return __uint_as_float(((unsigned)b) << 16);
}
__device__ __forceinline__ unsigned cvt2(float a, float b) {
    __hip_bfloat162 h2 = __float22bfloat162_rn(make_float2(a, b));
    return *reinterpret_cast<unsigned*>(&h2);
}

union abits {
    short8 s8;
    unsigned u[4];
};

// prep: W -> bf16 MFMA B-fragments; also inits gcursor (NBKT entries).
__global__ __launch_bounds__(256) void k_wprep(const float* __restrict__ W,
                                               short* __restrict__ Wfrag,
                                               int* __restrict__ gcursor) {
    int idx = blockIdx.x * 256 + threadIdx.x;  // 64 blocks -> 16384
    if (idx < NBKT) gcursor[idx] = idx * CAP;
    if (idx >= 8 * 4 * 64 * 8) return;
    int j = idx & 7;
    int l = (idx >> 3) & 63;
    int t = (idx >> 9) & 3;
    int s = idx >> 11;
    int k = s * 32 + (l >> 4) * 8 + j;
    int n = t * 16 + (l & 15);
    Wfrag[idx] = (short)f2b(W[k * OUT_F + n]);
}

// Fused: blocks [0,BIN_NB) bin edges into bucket regions (src>>7);
//        blocks [BIN_NB, BIN_NB+GEMM_NB) do the MFMA GEMM.
__global__ __launch_bounds__(256, 2) void k_bc(
    const float* __restrict__ h, const short* __restrict__ Wfrag,
    const float* __restrict__ a, unsigned short* __restrict__ Whb,
    float* __restrict__ ew, const int* __restrict__ ei,
    int* __restrict__ gcursor, int* __restrict__ binned) {
    __shared__ int bc[NBKT];

    if (blockIdx.x < BIN_NB) {
        // ---- binning branch ----
        const int t = threadIdx.x;
        for (int i = t; i < NBKT; i += 256) bc[i] = 0;
        __syncthreads();

        int s[16], d[16];
        const int e0 = blockIdx.x * BIN_EPB;
#pragma unroll
        for (int i = 0; i < 16; ++i) {
            int e = e0 + i * 256 + t;
            if (e < N_EDGES) {
                s[i] = ei[e];
                d[i] = ei[N_EDGES + e];
                atomicAdd(&bc[s[i] >> 7], 1);
            } else {
                s[i] = -1;
            }
        }
        __syncthreads();
        for (int i = t; i < NBKT; i += 256) {
            int cnt = bc[i];
            bc[i] = cnt ? atomicAdd(&gcursor[i], cnt) : 0;
        }
        __syncthreads();
#pragma unroll
        for (int i = 0; i < 16; ++i) {
            if (s[i] >= 0) {
                int bkt = s[i] >> 7;
                int idx = atomicAdd(&bc[bkt], 1);
                if (idx < (bkt + 1) * CAP)
                    binned[idx] = ((s[i] & 127) << 16) | d[i];
            }
        }
        return;
    }

    // ---- GEMM branch: Wh(bf16) = leaky_relu(h@W); ew = exp(Wh@a2) ----
    const int bid = blockIdx.x - BIN_NB;
    const int tid = threadIdx.x;
    const int wid = tid >> 6;
    const int l = tid & 63;
    const int lo = l & 15;
    const int g = l >> 4;
    const int m0 = (bid * 4 + wid) * 32;

    short8 b[8][4];
#pragma unroll
    for (int s = 0; s < 8; ++s)
#pragma unroll
        for (int t = 0; t < 4; ++t)
            b[s][t] = *(const short8*)&Wfrag[(((s * 4 + t) * 64) + l) * 8];

    const int r0 = m0 + lo;
    const int r1 = m0 + 16 + lo;
    const int r0c = r0 < N_NODES ? r0 : N_NODES - 1;
    const int r1c = r1 < N_NODES ? r1 : N_NODES - 1;

    f32x4 acc[2][4];
#pragma unroll
    for (int mt = 0; mt < 2; ++mt)
#pragma unroll
        for (int t = 0; t < 4; ++t)
            acc[mt][t] = (f32x4){0.f, 0.f, 0.f, 0.f};

#pragma unroll
    for (int s = 0; s < 8; ++s) {
        const float* p0 = &h[(size_t)r0c * IN_F + s * 32 + g * 8];
        const float* p1 = &h[(size_t)r1c * IN_F + s * 32 + g * 8];
        float4 x0 = *(const float4*)p0;
        float4 y0 = *(const float4*)(p0 + 4);
        float4 x1 = *(const float4*)p1;
        float4 y1 = *(const float4*)(p1 + 4);
        abits A0, A1;
        A0.u[0] = cvt2(x0.x, x0.y);
        A0.u[1] = cvt2(x0.z, x0.w);
        A0.u[2] = cvt2(y0.x, y0.y);
        A0.u[3] = cvt2(y0.z, y0.w);
        A1.u[0] = cvt2(x1.x, x1.y);
        A1.u[1] = cvt2(x1.z, x1.w);
        A1.u[2] = cvt2(y1.x, y1.y);
        A1.u[3] = cvt2(y1.z, y1.w);
#pragma unroll
        for (int t = 0; t < 4; ++t) {
            acc[0][t] = __builtin_amdgcn_mfma_f32_16x16x32_bf16(
                A0.s8, b[s][t], acc[0][t], 0, 0, 0);
            acc[1][t] = __builtin_amdgcn_mfma_f32_16x16x32_bf16(
                A1.s8, b[s][t], acc[1][t], 0, 0, 0);
        }
    }

    float a2v[4];
#pragma unroll
    for (int t = 0; t < 4; ++t) a2v[t] = a[OUT_F + t * 16 + lo];

#pragma unroll
    for (int mt = 0; mt < 2; ++mt) {
        float p[4];
#pragma unroll
        for (int reg = 0; reg < 4; ++reg) {
            float pp = 0.f;
#pragma unroll
            for (int t = 0; t < 4; ++t) {
                float v = acc[mt][t][reg];
                v = v > 0.f ? v : ALPHA * v;
                acc[mt][t][reg] = v;
                pp += v * a2v[t];
            }
            p[reg] = pp;
        }
#pragma unroll
        for (int reg = 0; reg < 4; ++reg) {
#pragma unroll
            for (int mask = 1; mask < 16; mask <<= 1)
                p[reg] += __shfl_xor(p[reg], mask, 64);
        }
        const int rbase = m0 + mt * 16 + g * 4;
        if (lo == 0) {
#pragma unroll
            for (int reg = 0; reg < 4; ++reg)
                if (rbase + reg < N_NODES) ew[rbase + reg] = __expf(p[reg]);
        }
#pragma unroll
        for (int reg = 0; reg < 4; ++reg) {
            int r = rbase + reg;
            if (r < N_NODES) {
#pragma unroll
                for (int t = 0; t < 4; ++t)
                    Whb[(size_t)r * OUT_F + t * 16 + lo] =
                        f2b(acc[mt][t][reg]);
            }
        }
    }
}

// Fused order+aggregate (round-8 structure): one block per 128-node bucket.
// Edges reg-cached (<=3/thread), in-LDS hist+scan+placement, then per-node
// sorted gather aggregate + ELU.
__global__ __launch_bounds__(1024) void k_fuse(
    const int* __restrict__ binned, const int* __restrict__ gcursor,
    const float* __restrict__ ew, const unsigned short* __restrict__ Whb,
    float* __restrict__ out) {
    __shared__ unsigned short ldst[CAP];
    __shared__ int hist[NPB];
    __shared__ int sstart[NPB];
    __shared__ int sc[NPB];
    const int t = threadIdx.x;
    const int b = blockIdx.x;

    int mycnt = gcursor[b] - b * CAP;
    mycnt = mycnt < 0 ? 0 : (mycnt > CAP ? CAP : mycnt);
    const int rb = b * CAP;

    if (t < NPB) hist[t] = 0;
    __syncthreads();

    // read edges into named registers (CAP <= 3*1024), histogram
    int p0 = -1, p1 = -1, p2 = -1;
    if (t < mycnt) {
        p0 = binned[rb + t];
        atomicAdd(&hist[p0 >> 16], 1);
    }
    if (t + 1024 < mycnt) {
        p1 = binned[rb + t + 1024];
        atomicAdd(&hist[p1 >> 16], 1);
    }
    if (t + 2048 < mycnt) {
        p2 = binned[rb + t + 2048];
        atomicAdd(&hist[p2 >> 16], 1);
    }
    __syncthreads();

    // exclusive scan over NPB=128 entries
    int my = 0;
    if (t < NPB) { my = hist[t]; sc[t] = my; }
    __syncthreads();
    for (int o = 1; o < NPB; o <<= 1) {
        int u = 0;
        if (t < NPB && t >= o) u = sc[t - o];
        __syncthreads();
        if (t < NPB) sc[t] += u;
        __syncthreads();
    }
    if (t < NPB) {
        sstart[t] = sc[t] - my;
        hist[t] = sc[t] - my;   // reuse as cursor
    }
    __syncthreads();

    // place
    if (p0 >= 0) ldst[atomicAdd(&hist[p0 >> 16], 1)] = (unsigned short)(p0 & 0xFFFF);
    if (p1 >= 0) ldst[atomicAdd(&hist[p1 >> 16], 1)] = (unsigned short)(p1 & 0xFFFF);
    if (p2 >= 0) ldst[atomicAdd(&hist[p2 >> 16], 1)] = (unsigned short)(p2 & 0xFFFF);
    __syncthreads();

    // aggregate: 16 waves x 8 nodes; 8 edge-slots x 8 feature-lanes
    const int wave = t >> 6;
    const int lane = t & 63;
    const int slot = lane >> 3;
    const int fl = lane & 7;

    for (int ii = 0; ii < 8; ++ii) {
        const int i = wave * 8 + ii;
        const int node = b * NPB + i;
        if (node >= N_NODES) break;   // wave-uniform
        const int start = sstart[i];
        const int end = (i < NPB - 1) ? sstart[i + 1] : mycnt;

        float acc[8] = {0.f, 0.f, 0.f, 0.f, 0.f, 0.f, 0.f, 0.f};
        float den = 0.f;
        for (int j0 = start; j0 < end; j0 += 8) {
            int j = j0 + slot;
            bool act = j < end;
            int dd = act ? (int)ldst[j] : 0;
            float w = act ? ew[dd] : 0.f;
            u16x8 wv = *(const u16x8*)&Whb[(size_t)dd * OUT_F + fl * 8];
            den += w;
#pragma unroll
            for (int k = 0; k < 8; ++k) acc[k] += w * b2f(wv[k]);
        }
#pragma unroll
        for (int mask = 8; mask <= 32; mask <<= 1) {
#pragma unroll
            for (int k = 0; k < 8; ++k)
                acc[k] += __shfl_xor(acc[k], mask, 64);
            den += __shfl_xor(den, mask, 64);
        }

        if (slot == 0) {
            float4 r0, r1;
            if (end > start) {
                float inv = 1.f / den;
                float v;
                v = acc[0] * inv; r0.x = v > 0.f ? v : expm1f(v);
                v = acc[1] * inv; r0.y = v > 0.f ? v : expm1f(v);
                v = acc[2] * inv; r0.z = v > 0.f ? v : expm1f(v);
                v = acc[3] * inv; r0.w = v > 0.f ? v : expm1f(v);
                v = acc[4] * inv; r1.x = v > 0.f ? v : expm1f(v);
                v = acc[5] * inv; r1.y = v > 0.f ? v : expm1f(v);
                v = acc[6] * inv; r1.z = v > 0.f ? v : expm1f(v);
                v = acc[7] * inv; r1.w = v > 0.f ? v : expm1f(v);
            } else {
                r0 = make_float4(0.f, 0.f, 0.f, 0.f);
                r1 = r0;
            }
            *(float4*)&out[(size_t)node * OUT_F + fl * 8] = r0;
            *(float4*)&out[(size_t)node * OUT_F + fl * 8 + 4] = r1;
        }
    }
}

extern "C" void kernel_launch(void* const* d_in, const int* in_sizes, int n_in,
                              void* d_out, int out_size, void* d_ws,
                              size_t ws_size, hipStream_t stream) {
    const float* h = (const float*)d_in[0];
    const int* ei = (const int*)d_in[1];
    const float* W = (const float*)d_in[2];
    const float* a = (const float*)d_in[3];
    float* out = (float*)d_out;

    float* ws = (float*)d_ws;
    unsigned short* Whb = (unsigned short*)ws;   // 3.2M bf16 = 1.6M floats
    float* ew = ws + 1600000;                    // 50,000
    short* Wfrag = (short*)(ws + 1650000);       // 16,384 bf16
    int* gcursor = (int*)(ws + 1658192);         // 512 (NBKT=391 used)
    int* binned = (int*)(ws + 1658704);          // NBKT*CAP = 1,000,960 ints

    k_wprep<<<64, 256, 0, stream>>>(W, Wfrag, gcursor);
    k_bc<<<BIN_NB + GEMM_NB, 256, 0, stream>>>(h, Wfrag, a, Whb, ew, ei,
                                               gcursor, binned);
    k_fuse<<<NBKT, 1024, 0, stream>>>(binned, gcursor, ew, Whb, out);
}

// Round 11
// 55.284 us; speedup vs baseline: 7.4600x; 1.1875x over previous
//
#include <hip/hip_runtime.h>
#include <hip/hip_bf16.h>
#include <math.h>

#define N_NODES 50000
#define N_EDGES 800000
#define IN_F 256
#define OUT_F 64
#define ALPHA 0.2f

#define NPB 64                  // nodes per bucket
#define NBKT 782                // ceil(50000/64)
#define CAP 1536                // bucket capacity (mean 1024 + ~16 sigma)
#define BIN_EPB 4096
#define BIN_NB 196              // ceil(800000/4096)
#define GEMM_NB 391             // ceil(50000/128)

typedef __attribute__((ext_vector_type(8))) short short8;
typedef __attribute__((ext_vector_type(8))) unsigned short u16x8;
typedef __attribute__((ext_vector_type(4))) float f32x4;

__device__ __forceinline__ unsigned short f2b(float f) {
    unsigned u = __float_as_uint(f);
    unsigned r = (u + 0x7fffu + ((u >> 16) & 1u)) >> 16;  // RNE
    return (unsigned short)r;
}
__device__ __forceinline__ float b2f(unsigned short b) {
    return __uint_as_float(((unsigned)b) << 16);
}
__device__ __forceinline__ unsigned cvt2(float a, float b) {
    __hip_bfloat162 h2 = __float22bfloat162_rn(make_float2(a, b));
    return *reinterpret_cast<unsigned*>(&h2);
}

union abits {
    short8 s8;
    unsigned u[4];
};

// prep: W -> bf16 MFMA B-fragments; also inits gcursor (NBKT entries).
__global__ __launch_bounds__(256) void k_wprep(const float* __restrict__ W,
                                               short* __restrict__ Wfrag,
                                               int* __restrict__ gcursor) {
    int idx = blockIdx.x * 256 + threadIdx.x;  // 64 blocks -> 16384
    if (idx < NBKT) gcursor[idx] = idx * CAP;
    if (idx >= 8 * 4 * 64 * 8) return;
    int j = idx & 7;
    int l = (idx >> 3) & 63;
    int t = (idx >> 9) & 3;
    int s = idx >> 11;
    int k = s * 32 + (l >> 4) * 8 + j;
    int n = t * 16 + (l & 15);
    Wfrag[idx] = (short)f2b(W[k * OUT_F + n]);
}

// Fused: blocks [0,BIN_NB) bin edges into bucket regions (src>>6);
//        blocks [BIN_NB, BIN_NB+GEMM_NB) do the MFMA GEMM.
__global__ __launch_bounds__(256, 2) void k_bc(
    const float* __restrict__ h, const short* __restrict__ Wfrag,
    const float* __restrict__ a, unsigned short* __restrict__ Whb,
    float* __restrict__ ew, const int* __restrict__ ei,
    int* __restrict__ gcursor, int* __restrict__ binned) {
    __shared__ int bc[NBKT];

    if (blockIdx.x < BIN_NB) {
        // ---- binning branch ----
        const int t = threadIdx.x;
        for (int i = t; i < NBKT; i += 256) bc[i] = 0;
        __syncthreads();

        int s[16], d[16];
        const int e0 = blockIdx.x * BIN_EPB;
#pragma unroll
        for (int i = 0; i < 16; ++i) {
            int e = e0 + i * 256 + t;
            if (e < N_EDGES) {
                s[i] = ei[e];
                d[i] = ei[N_EDGES + e];
                atomicAdd(&bc[s[i] >> 6], 1);
            } else {
                s[i] = -1;
            }
        }
        __syncthreads();
        for (int i = t; i < NBKT; i += 256) {
            int cnt = bc[i];
            bc[i] = cnt ? atomicAdd(&gcursor[i], cnt) : 0;
        }
        __syncthreads();
#pragma unroll
        for (int i = 0; i < 16; ++i) {
            if (s[i] >= 0) {
                int bkt = s[i] >> 6;
                int idx = atomicAdd(&bc[bkt], 1);
                if (idx < (bkt + 1) * CAP)
                    binned[idx] = ((s[i] & 63) << 16) | d[i];
            }
        }
        return;
    }

    // ---- GEMM branch: Wh(bf16) = leaky_relu(h@W); ew = exp(Wh@a2) ----
    const int bid = blockIdx.x - BIN_NB;
    const int tid = threadIdx.x;
    const int wid = tid >> 6;
    const int l = tid & 63;
    const int lo = l & 15;
    const int g = l >> 4;
    const int m0 = (bid * 4 + wid) * 32;

    short8 b[8][4];
#pragma unroll
    for (int s = 0; s < 8; ++s)
#pragma unroll
        for (int t = 0; t < 4; ++t)
            b[s][t] = *(const short8*)&Wfrag[(((s * 4 + t) * 64) + l) * 8];

    const int r0 = m0 + lo;
    const int r1 = m0 + 16 + lo;
    const int r0c = r0 < N_NODES ? r0 : N_NODES - 1;
    const int r1c = r1 < N_NODES ? r1 : N_NODES - 1;

    f32x4 acc[2][4];
#pragma unroll
    for (int mt = 0; mt < 2; ++mt)
#pragma unroll
        for (int t = 0; t < 4; ++t)
            acc[mt][t] = (f32x4){0.f, 0.f, 0.f, 0.f};

#pragma unroll
    for (int s = 0; s < 8; ++s) {
        const float* p0 = &h[(size_t)r0c * IN_F + s * 32 + g * 8];
        const float* p1 = &h[(size_t)r1c * IN_F + s * 32 + g * 8];
        float4 x0 = *(const float4*)p0;
        float4 y0 = *(const float4*)(p0 + 4);
        float4 x1 = *(const float4*)p1;
        float4 y1 = *(const float4*)(p1 + 4);
        abits A0, A1;
        A0.u[0] = cvt2(x0.x, x0.y);
        A0.u[1] = cvt2(x0.z, x0.w);
        A0.u[2] = cvt2(y0.x, y0.y);
        A0.u[3] = cvt2(y0.z, y0.w);
        A1.u[0] = cvt2(x1.x, x1.y);
        A1.u[1] = cvt2(x1.z, x1.w);
        A1.u[2] = cvt2(y1.x, y1.y);
        A1.u[3] = cvt2(y1.z, y1.w);
#pragma unroll
        for (int t = 0; t < 4; ++t) {
            acc[0][t] = __builtin_amdgcn_mfma_f32_16x16x32_bf16(
                A0.s8, b[s][t], acc[0][t], 0, 0, 0);
            acc[1][t] = __builtin_amdgcn_mfma_f32_16x16x32_bf16(
                A1.s8, b[s][t], acc[1][t], 0, 0, 0);
        }
    }

    float a2v[4];
#pragma unroll
    for (int t = 0; t < 4; ++t) a2v[t] = a[OUT_F + t * 16 + lo];

#pragma unroll
    for (int mt = 0; mt < 2; ++mt) {
        float p[4];
#pragma unroll
        for (int reg = 0; reg < 4; ++reg) {
            float pp = 0.f;
#pragma unroll
            for (int t = 0; t < 4; ++t) {
                float v = acc[mt][t][reg];
                v = v > 0.f ? v : ALPHA * v;
                acc[mt][t][reg] = v;
                pp += v * a2v[t];
            }
            p[reg] = pp;
        }
#pragma unroll
        for (int reg = 0; reg < 4; ++reg) {
#pragma unroll
            for (int mask = 1; mask < 16; mask <<= 1)
                p[reg] += __shfl_xor(p[reg], mask, 64);
        }
        const int rbase = m0 + mt * 16 + g * 4;
        if (lo == 0) {
#pragma unroll
            for (int reg = 0; reg < 4; ++reg)
                if (rbase + reg < N_NODES) ew[rbase + reg] = __expf(p[reg]);
        }
#pragma unroll
        for (int reg = 0; reg < 4; ++reg) {
            int r = rbase + reg;
            if (r < N_NODES) {
#pragma unroll
                for (int t = 0; t < 4; ++t)
                    Whb[(size_t)r * OUT_F + t * 16 + lo] =
                        f2b(acc[mt][t][reg]);
            }
        }
    }
}

// Fused order+aggregate: one 512-thread block per 64-node bucket.
// Edges reg-cached (<=3/thread), in-LDS hist + single-wave shuffle scan +
// placement, then 64 parallel 8-lane node-groups, no cross-lane reduction.
__global__ __launch_bounds__(512) void k_fuse(
    const int* __restrict__ binned, const int* __restrict__ gcursor,
    const float* __restrict__ ew, const unsigned short* __restrict__ Whb,
    float* __restrict__ out) {
    __shared__ unsigned short ldst[CAP];
    __shared__ int hist[NPB];
    __shared__ int sstart[NPB];
    const int t = threadIdx.x;
    const int b = blockIdx.x;

    int mycnt = gcursor[b] - b * CAP;
    mycnt = mycnt < 0 ? 0 : (mycnt > CAP ? CAP : mycnt);
    const int rb = b * CAP;

    if (t < NPB) hist[t] = 0;
    __syncthreads();

    // read edges into named registers (CAP <= 3*512), histogram
    int p0 = -1, p1 = -1, p2 = -1;
    if (t < mycnt) {
        p0 = binned[rb + t];
        atomicAdd(&hist[p0 >> 16], 1);
    }
    if (t + 512 < mycnt) {
        p1 = binned[rb + t + 512];
        atomicAdd(&hist[p1 >> 16], 1);
    }
    if (t + 1024 < mycnt) {
        p2 = binned[rb + t + 1024];
        atomicAdd(&hist[p2 >> 16], 1);
    }
    __syncthreads();

    // exclusive scan over NPB=64 entries: single-wave shuffle scan
    if (t < 64) {
        int my = hist[t];
        int x = my;
#pragma unroll
        for (int o = 1; o < 64; o <<= 1) {
            int u = __shfl_up(x, o, 64);
            if (t >= o) x += u;
        }
        sstart[t] = x - my;
        hist[t] = x - my;   // reuse as cursor
    }
    __syncthreads();

    // place
    if (p0 >= 0) ldst[atomicAdd(&hist[p0 >> 16], 1)] = (unsigned short)(p0 & 0xFFFF);
    if (p1 >= 0) ldst[atomicAdd(&hist[p1 >> 16], 1)] = (unsigned short)(p1 & 0xFFFF);
    if (p2 >= 0) ldst[atomicAdd(&hist[p2 >> 16], 1)] = (unsigned short)(p2 & 0xFFFF);
    __syncthreads();

    // aggregate: 64 groups x 8 lanes; group = node, lane owns 8 features
    const int grp = t >> 3;        // 0..63
    const int fl = t & 7;          // feature block: fl*8 .. fl*8+7
    const int node = b * NPB + grp;
    const int start = sstart[grp];
    const int end = (grp < NPB - 1) ? sstart[grp + 1] : mycnt;

    float acc[8] = {0.f, 0.f, 0.f, 0.f, 0.f, 0.f, 0.f, 0.f};
    float den = 0.f;
    for (int j = start; j < end; ++j) {
        int dd = (int)ldst[j];               // LDS broadcast within group
        float w = ew[dd];                    // same-address gather per group
        u16x8 wv = *(const u16x8*)&Whb[(size_t)dd * OUT_F + fl * 8];
        den += w;
#pragma unroll
        for (int k = 0; k < 8; ++k) acc[k] += w * b2f(wv[k]);
    }

    if (node < N_NODES) {
        float4 r0, r1;
        if (end > start) {
            float inv = 1.f / den;
            float v;
            v = acc[0] * inv; r0.x = v > 0.f ? v : expm1f(v);
            v = acc[1] * inv; r0.y = v > 0.f ? v : expm1f(v);
            v = acc[2] * inv; r0.z = v > 0.f ? v : expm1f(v);
            v = acc[3] * inv; r0.w = v > 0.f ? v : expm1f(v);
            v = acc[4] * inv; r1.x = v > 0.f ? v : expm1f(v);
            v = acc[5] * inv; r1.y = v > 0.f ? v : expm1f(v);
            v = acc[6] * inv; r1.z = v > 0.f ? v : expm1f(v);
            v = acc[7] * inv; r1.w = v > 0.f ? v : expm1f(v);
        } else {
            r0 = make_float4(0.f, 0.f, 0.f, 0.f);
            r1 = r0;
        }
        *(float4*)&out[(size_t)node * OUT_F + fl * 8] = r0;
        *(float4*)&out[(size_t)node * OUT_F + fl * 8 + 4] = r1;
    }
}

extern "C" void kernel_launch(void* const* d_in, const int* in_sizes, int n_in,
                              void* d_out, int out_size, void* d_ws,
                              size_t ws_size, hipStream_t stream) {
    const float* h = (const float*)d_in[0];
    const int* ei = (const int*)d_in[1];
    const float* W = (const float*)d_in[2];
    const float* a = (const float*)d_in[3];
    float* out = (float*)d_out;

    float* ws = (float*)d_ws;
    unsigned short* Whb = (unsigned short*)ws;   // 3.2M bf16 = 1.6M floats
    float* ew = ws + 1600000;                    // 50,000
    short* Wfrag = (short*)(ws + 1650000);       // 16,384 bf16
    int* gcursor = (int*)(ws + 1658192);         // 1,024 (NBKT=782 used)
    int* binned = (int*)(ws + 1659216);          // NBKT*CAP = 1,201,152 ints

    k_wprep<<<64, 256, 0, stream>>>(W, Wfrag, gcursor);
    k_bc<<<BIN_NB + GEMM_NB, 256, 0, stream>>>(h, Wfrag, a, Whb, ew, ei,
                                               gcursor, binned);
    k_fuse<<<NBKT, 512, 0, stream>>>(binned, gcursor, ew, Whb, out);
}

// Round 12
// 49.464 us; speedup vs baseline: 8.3377x; 1.1177x over previous
//
#include <hip/hip_runtime.h>
#include <hip/hip_bf16.h>
#include <math.h>

#define N_NODES 50000
#define N_EDGES 800000
#define IN_F 256
#define OUT_F 64
#define ALPHA 0.2f

#define NPB 64                  // nodes per bucket
#define NBKT 782                // ceil(50000/64)
#define CAP 1536                // bucket capacity (mean 1024 + ~16 sigma)
#define BIN_EPB 4096
#define BIN_NB 196              // ceil(800000/4096)
#define GEMM_NB 391             // ceil(50000/128)

typedef __attribute__((ext_vector_type(8))) short short8;
typedef __attribute__((ext_vector_type(8))) unsigned short u16x8;
typedef __attribute__((ext_vector_type(4))) float f32x4;

__device__ __forceinline__ unsigned short f2b(float f) {
    unsigned u = __float_as_uint(f);
    unsigned r = (u + 0x7fffu + ((u >> 16) & 1u)) >> 16;  // RNE
    return (unsigned short)r;
}
__device__ __forceinline__ float b2f(unsigned short b) {
    return __uint_as_float(((unsigned)b) << 16);
}
__device__ __forceinline__ unsigned cvt2(float a, float b) {
    __hip_bfloat162 h2 = __float22bfloat162_rn(make_float2(a, b));
    return *reinterpret_cast<unsigned*>(&h2);
}

union abits {
    short8 s8;
    unsigned u[4];
};

// prep: W -> bf16 MFMA B-fragments; also inits gcursor (NBKT entries).
__global__ __launch_bounds__(256) void k_wprep(const float* __restrict__ W,
                                               short* __restrict__ Wfrag,
                                               int* __restrict__ gcursor) {
    int idx = blockIdx.x * 256 + threadIdx.x;  // 64 blocks -> 16384
    if (idx < NBKT) gcursor[idx] = idx * CAP;
    if (idx >= 8 * 4 * 64 * 8) return;
    int j = idx & 7;
    int l = (idx >> 3) & 63;
    int t = (idx >> 9) & 3;
    int s = idx >> 11;
    int k = s * 32 + (l >> 4) * 8 + j;
    int n = t * 16 + (l & 15);
    Wfrag[idx] = (short)f2b(W[k * OUT_F + n]);
}

// Fused: blocks [0,BIN_NB) bin edges into bucket regions (src>>6);
//        blocks [BIN_NB, BIN_NB+GEMM_NB) do the MFMA GEMM with Wfrag in LDS.
__global__ __launch_bounds__(256, 4) void k_bc(
    const float* __restrict__ h, const short* __restrict__ Wfrag,
    const float* __restrict__ a, unsigned short* __restrict__ Whb,
    float* __restrict__ ew, const int* __restrict__ ei,
    int* __restrict__ gcursor, int* __restrict__ binned) {
    __shared__ int bc[NBKT];
    __shared__ short8 wlds[2048];   // 32 fragments x 64 lanes = 32 KB

    if (blockIdx.x < BIN_NB) {
        // ---- binning branch ----
        const int t = threadIdx.x;
        for (int i = t; i < NBKT; i += 256) bc[i] = 0;
        __syncthreads();

        int s[16], d[16];
        const int e0 = blockIdx.x * BIN_EPB;
#pragma unroll
        for (int i = 0; i < 16; ++i) {
            int e = e0 + i * 256 + t;
            if (e < N_EDGES) {
                s[i] = ei[e];
                d[i] = ei[N_EDGES + e];
                atomicAdd(&bc[s[i] >> 6], 1);
            } else {
                s[i] = -1;
            }
        }
        __syncthreads();
        for (int i = t; i < NBKT; i += 256) {
            int cnt = bc[i];
            bc[i] = cnt ? atomicAdd(&gcursor[i], cnt) : 0;
        }
        __syncthreads();
#pragma unroll
        for (int i = 0; i < 16; ++i) {
            if (s[i] >= 0) {
                int bkt = s[i] >> 6;
                int idx = atomicAdd(&bc[bkt], 1);
                if (idx < (bkt + 1) * CAP)
                    binned[idx] = ((s[i] & 63) << 16) | d[i];
            }
        }
        return;
    }

    // ---- GEMM branch: Wh(bf16) = leaky_relu(h@W); ew = exp(Wh@a2) ----
    const int bid = blockIdx.x - BIN_NB;
    const int tid = threadIdx.x;
    const int wid = tid >> 6;
    const int l = tid & 63;
    const int lo = l & 15;
    const int g = l >> 4;
    const int m0 = (bid * 4 + wid) * 32;

    // stage all 32 B-fragments (32 KB) into LDS, coalesced, linear
    {
        int4* dstv = (int4*)wlds;
        const int4* srcv = (const int4*)Wfrag;
#pragma unroll
        for (int i = 0; i < 8; ++i) dstv[tid + i * 256] = srcv[tid + i * 256];
    }
    __syncthreads();

    const int r0 = m0 + lo;
    const int r1 = m0 + 16 + lo;
    const int r0c = r0 < N_NODES ? r0 : N_NODES - 1;
    const int r1c = r1 < N_NODES ? r1 : N_NODES - 1;

    f32x4 acc[2][4];
#pragma unroll
    for (int mt = 0; mt < 2; ++mt)
#pragma unroll
        for (int t = 0; t < 4; ++t)
            acc[mt][t] = (f32x4){0.f, 0.f, 0.f, 0.f};

#pragma unroll
    for (int s = 0; s < 8; ++s) {
        const float* p0 = &h[(size_t)r0c * IN_F + s * 32 + g * 8];
        const float* p1 = &h[(size_t)r1c * IN_F + s * 32 + g * 8];
        float4 x0 = *(const float4*)p0;
        float4 y0 = *(const float4*)(p0 + 4);
        float4 x1 = *(const float4*)p1;
        float4 y1 = *(const float4*)(p1 + 4);
        abits A0, A1;
        A0.u[0] = cvt2(x0.x, x0.y);
        A0.u[1] = cvt2(x0.z, x0.w);
        A0.u[2] = cvt2(y0.x, y0.y);
        A0.u[3] = cvt2(y0.z, y0.w);
        A1.u[0] = cvt2(x1.x, x1.y);
        A1.u[1] = cvt2(x1.z, x1.w);
        A1.u[2] = cvt2(y1.x, y1.y);
        A1.u[3] = cvt2(y1.z, y1.w);
#pragma unroll
        for (int t = 0; t < 4; ++t) {
            short8 bf = wlds[(s * 4 + t) * 64 + l];   // ds_read_b128, conflict-free
            acc[0][t] = __builtin_amdgcn_mfma_f32_16x16x32_bf16(
                A0.s8, bf, acc[0][t], 0, 0, 0);
            acc[1][t] = __builtin_amdgcn_mfma_f32_16x16x32_bf16(
                A1.s8, bf, acc[1][t], 0, 0, 0);
        }
    }

    float a2v[4];
#pragma unroll
    for (int t = 0; t < 4; ++t) a2v[t] = a[OUT_F + t * 16 + lo];

#pragma unroll
    for (int mt = 0; mt < 2; ++mt) {
        float p[4];
#pragma unroll
        for (int reg = 0; reg < 4; ++reg) {
            float pp = 0.f;
#pragma unroll
            for (int t = 0; t < 4; ++t) {
                float v = acc[mt][t][reg];
                v = v > 0.f ? v : ALPHA * v;
                acc[mt][t][reg] = v;
                pp += v * a2v[t];
            }
            p[reg] = pp;
        }
#pragma unroll
        for (int reg = 0; reg < 4; ++reg) {
#pragma unroll
            for (int mask = 1; mask < 16; mask <<= 1)
                p[reg] += __shfl_xor(p[reg], mask, 64);
        }
        const int rbase = m0 + mt * 16 + g * 4;
        if (lo == 0) {
#pragma unroll
            for (int reg = 0; reg < 4; ++reg)
                if (rbase + reg < N_NODES) ew[rbase + reg] = __expf(p[reg]);
        }
#pragma unroll
        for (int reg = 0; reg < 4; ++reg) {
            int r = rbase + reg;
            if (r < N_NODES) {
#pragma unroll
                for (int t = 0; t < 4; ++t)
                    Whb[(size_t)r * OUT_F + t * 16 + lo] =
                        f2b(acc[mt][t][reg]);
            }
        }
    }
}

// Fused order+aggregate: one 512-thread block per 64-node bucket.
// Edges reg-cached (<=3/thread), in-LDS hist + single-wave shuffle scan +
// placement, then 64 parallel 8-lane node-groups, no cross-lane reduction.
__global__ __launch_bounds__(512) void k_fuse(
    const int* __restrict__ binned, const int* __restrict__ gcursor,
    const float* __restrict__ ew, const unsigned short* __restrict__ Whb,
    float* __restrict__ out) {
    __shared__ unsigned short ldst[CAP];
    __shared__ int hist[NPB];
    __shared__ int sstart[NPB];
    const int t = threadIdx.x;
    const int b = blockIdx.x;

    int mycnt = gcursor[b] - b * CAP;
    mycnt = mycnt < 0 ? 0 : (mycnt > CAP ? CAP : mycnt);
    const int rb = b * CAP;

    if (t < NPB) hist[t] = 0;
    __syncthreads();

    // read edges into named registers (CAP <= 3*512), histogram
    int p0 = -1, p1 = -1, p2 = -1;
    if (t < mycnt) {
        p0 = binned[rb + t];
        atomicAdd(&hist[p0 >> 16], 1);
    }
    if (t + 512 < mycnt) {
        p1 = binned[rb + t + 512];
        atomicAdd(&hist[p1 >> 16], 1);
    }
    if (t + 1024 < mycnt) {
        p2 = binned[rb + t + 1024];
        atomicAdd(&hist[p2 >> 16], 1);
    }
    __syncthreads();

    // exclusive scan over NPB=64 entries: single-wave shuffle scan
    if (t < 64) {
        int my = hist[t];
        int x = my;
#pragma unroll
        for (int o = 1; o < 64; o <<= 1) {
            int u = __shfl_up(x, o, 64);
            if (t >= o) x += u;
        }
        sstart[t] = x - my;
        hist[t] = x - my;   // reuse as cursor
    }
    __syncthreads();

    // place
    if (p0 >= 0) ldst[atomicAdd(&hist[p0 >> 16], 1)] = (unsigned short)(p0 & 0xFFFF);
    if (p1 >= 0) ldst[atomicAdd(&hist[p1 >> 16], 1)] = (unsigned short)(p1 & 0xFFFF);
    if (p2 >= 0) ldst[atomicAdd(&hist[p2 >> 16], 1)] = (unsigned short)(p2 & 0xFFFF);
    __syncthreads();

    // aggregate: 64 groups x 8 lanes; group = node, lane owns 8 features
    const int grp = t >> 3;        // 0..63
    const int fl = t & 7;          // feature block: fl*8 .. fl*8+7
    const int node = b * NPB + grp;
    const int start = sstart[grp];
    const int end = (grp < NPB - 1) ? sstart[grp + 1] : mycnt;

    float acc[8] = {0.f, 0.f, 0.f, 0.f, 0.f, 0.f, 0.f, 0.f};
    float den = 0.f;
    for (int j = start; j < end; ++j) {
        int dd = (int)ldst[j];               // LDS broadcast within group
        float w = ew[dd];                    // same-address gather per group
        u16x8 wv = *(const u16x8*)&Whb[(size_t)dd * OUT_F + fl * 8];
        den += w;
#pragma unroll
        for (int k = 0; k < 8; ++k) acc[k] += w * b2f(wv[k]);
    }

    if (node < N_NODES) {
        float4 r0, r1;
        if (end > start) {
            float inv = 1.f / den;
            float v;
            v = acc[0] * inv; r0.x = v > 0.f ? v : expm1f(v);
            v = acc[1] * inv; r0.y = v > 0.f ? v : expm1f(v);
            v = acc[2] * inv; r0.z = v > 0.f ? v : expm1f(v);
            v = acc[3] * inv; r0.w = v > 0.f ? v : expm1f(v);
            v = acc[4] * inv; r1.x = v > 0.f ? v : expm1f(v);
            v = acc[5] * inv; r1.y = v > 0.f ? v : expm1f(v);
            v = acc[6] * inv; r1.z = v > 0.f ? v : expm1f(v);
            v = acc[7] * inv; r1.w = v > 0.f ? v : expm1f(v);
        } else {
            r0 = make_float4(0.f, 0.f, 0.f, 0.f);
            r1 = r0;
        }
        *(float4*)&out[(size_t)node * OUT_F + fl * 8] = r0;
        *(float4*)&out[(size_t)node * OUT_F + fl * 8 + 4] = r1;
    }
}

extern "C" void kernel_launch(void* const* d_in, const int* in_sizes, int n_in,
                              void* d_out, int out_size, void* d_ws,
                              size_t ws_size, hipStream_t stream) {
    const float* h = (const float*)d_in[0];
    const int* ei = (const int*)d_in[1];
    const float* W = (const float*)d_in[2];
    const float* a = (const float*)d_in[3];
    float* out = (float*)d_out;

    float* ws = (float*)d_ws;
    unsigned short* Whb = (unsigned short*)ws;   // 3.2M bf16 = 1.6M floats
    float* ew = ws + 1600000;                    // 50,000
    short* Wfrag = (short*)(ws + 1650000);       // 16,384 bf16
    int* gcursor = (int*)(ws + 1658192);         // 1,024 (NBKT=782 used)
    int* binned = (int*)(ws + 1659216);          // NBKT*CAP = 1,201,152 ints

    k_wprep<<<64, 256, 0, stream>>>(W, Wfrag, gcursor);
    k_bc<<<BIN_NB + GEMM_NB, 256, 0, stream>>>(h, Wfrag, a, Whb, ew, ei,
                                               gcursor, binned);
    k_fuse<<<NBKT, 512, 0, stream>>>(binned, gcursor, ew, Whb, out);
}